// Round 2
// baseline (245.170 us; speedup 1.0000x reference)
//
#include <hip/hip_runtime.h>

// MultiScaleRoIAlign, LDS-footprint-staged version.
// Block = (roi, chunk of CH=8 channels). Phase A: 28 threads compute per-sample
// bilinear params (shared across channels). Phase B: coalesced staging of the
// ROI's feature footprint into LDS (odd pitch to spread banks). Phase C: each
// output (ch,bin) does 16 ds_read gathers instead of 16 divergent global loads.
// Footprint bound: level heuristic keeps fwp*fh <= ~940 (cap 960, with a
// direct-global fallback path for safety).

#define ROI_OUT 7
#define NSAMP   14            // ROI_OUT * SR
#define C_TOT   256
#define N_PER_B 256
#define CH      8             // channels per block
#define NCHUNK  (C_TOT / CH)  // 32
#define FP_CAP  960           // floats per channel footprint tile
#define BINS    (ROI_OUT * ROI_OUT)

__global__ __launch_bounds__(256)
void msroi_kernel(const float* __restrict__ f0, const float* __restrict__ f1,
                  const float* __restrict__ f2, const float* __restrict__ f3,
                  const float* __restrict__ boxes, float* __restrict__ out)
{
    __shared__ float fp[CH * FP_CAP];   // 30 KB
    __shared__ int4  pY[NSAMP];         // {y0, y1, frac_bits, valid_bits}
    __shared__ int4  pX[NSAMP];

    const int tid   = threadIdx.x;
    const int roi   = blockIdx.x / NCHUNK;
    const int chunk = blockIdx.x - roi * NCHUNK;
    const int b     = roi / N_PER_B;
    const int c0    = chunk * CH;

    // ---- box + level (wave-uniform, redundant per thread) ----
    const float* bx = boxes + (size_t)roi * 4;
    float bx1 = bx[0], by1 = bx[1], bx2 = bx[2], by2 = bx[3];

    float area = (bx2 - bx1) * (by2 - by1);
    float s    = sqrtf(area);
    float lvlf = floorf(4.0f + log2f(s * (1.0f / 224.0f)) + 1e-6f);
    lvlf = fminf(fmaxf(lvlf, 2.0f), 5.0f);
    int level = (int)lvlf - 2;

    const float* feat; int H, W; float scale;
    switch (level) {
        case 0:  feat = f0; H = 200; W = 200; scale = 0.25f;    break;
        case 1:  feat = f1; H = 100; W = 100; scale = 0.125f;   break;
        case 2:  feat = f2; H = 50;  W = 50;  scale = 0.0625f;  break;
        default: feat = f3; H = 25;  W = 25;  scale = 0.03125f; break;
    }

    float x1 = bx1 * scale, y1 = by1 * scale;
    float roi_w = fmaxf(bx2 * scale - x1, 1.0f);
    float roi_h = fmaxf(by2 * scale - y1, 1.0f);
    float bin_w = roi_w * (1.0f / ROI_OUT);
    float bin_h = roi_h * (1.0f / ROI_OUT);

    // ---- phase A: per-sample params (14 x-samples, 14 y-samples) ----
    if (tid < 2 * NSAMP) {
        bool isy = tid >= NSAMP;
        int  j   = isy ? tid - NSAMP : tid;
        int  pb  = j >> 1, sub = j & 1;
        float start = isy ? y1 : x1;
        float bsz   = isy ? bin_h : bin_w;
        int   lim   = isy ? H : W;
        // ss = start + bin_idx*bsz + (sub+0.5)*bsz/2   (reference math)
        float ss = start + (float)pb * bsz + ((float)sub + 0.5f) * bsz * 0.5f;
        float v  = (ss >= -1.0f && ss <= (float)lim) ? 1.0f : 0.0f;
        float cc = fminf(fmaxf(ss, 0.0f), (float)lim - 1.0f);
        int   i0 = (int)floorf(cc);
        int   i1 = min(i0 + 1, lim - 1);
        float l  = cc - (float)i0;
        int4 pk;
        pk.x = i0; pk.y = i1;
        pk.z = __float_as_int(l);
        pk.w = __float_as_int(v);
        if (isy) pY[j] = pk; else pX[j] = pk;
    }
    __syncthreads();

    // footprint bounds (samples monotone in j, indices pre-clipped to [0,lim-1])
    const int xlo = pX[0].x, xhi = pX[NSAMP - 1].y;
    const int ylo = pY[0].x, yhi = pY[NSAMP - 1].y;
    const int fw  = xhi - xlo + 1;
    const int fh  = yhi - ylo + 1;
    const int fwp = fw | 1;            // odd pitch -> fewer LDS bank conflicts
    const int fsz = fw * fh;
    const size_t plane_sz = (size_t)(H * W);
    const float* base0 = feat + ((size_t)(b * C_TOT + c0)) * plane_sz;
    const int robase = (roi * C_TOT + c0) * BINS;

    if (fwp * fh <= FP_CAP) {
        // ---- phase B: coalesced staging, linear index with incremental div ----
        int row0 = tid / fw;                 // one real division
        int rx0  = tid - row0 * fw;
        int drow = 256 / fw;
        int drx  = 256 - drow * fw;          // < fw, so single-carry per step
        for (int ch = 0; ch < CH; ++ch) {
            const float* plane = base0 + (size_t)ch * plane_sz
                                 + (size_t)ylo * W + xlo;
            float* dst = &fp[ch * FP_CAP];
            int row = row0, rx = rx0;
            for (int p = tid; p < fsz; p += 256) {
                dst[row * fwp + rx] = plane[row * W + rx];
                rx += drx; row += drow;
                if (rx >= fw) { rx -= fw; row += 1; }
            }
        }
        __syncthreads();

        // ---- phase C: gather from LDS ----
        for (int o = tid; o < CH * BINS; o += 256) {
            int ch  = o / BINS;
            int bin = o - ch * BINS;
            int ph  = bin / ROI_OUT;
            int pw  = bin - ph * ROI_OUT;
            const float* chb = &fp[ch * FP_CAP];
            float acc = 0.0f;
            #pragma unroll
            for (int sy = 0; sy < 2; ++sy) {
                int4 py  = pY[2 * ph + sy];
                int  r0  = (py.x - ylo) * fwp;
                int  r1  = (py.y - ylo) * fwp;
                float ly = __int_as_float(py.z);
                float vy = __int_as_float(py.w);
                float hy = 1.0f - ly;
                #pragma unroll
                for (int sx = 0; sx < 2; ++sx) {
                    int4 px  = pX[2 * pw + sx];
                    int  cx0 = px.x - xlo, cx1 = px.y - xlo;
                    float lx = __int_as_float(px.z);
                    float vx = __int_as_float(px.w);
                    float hx = 1.0f - lx;
                    float v00 = chb[r0 + cx0], v01 = chb[r0 + cx1];
                    float v10 = chb[r1 + cx0], v11 = chb[r1 + cx1];
                    acc += vy * vx * (hy * (hx * v00 + lx * v01)
                                    + ly * (hx * v10 + lx * v11));
                }
            }
            out[robase + o] = acc * 0.25f;   // mean over 4 samples
        }
    } else {
        // ---- fallback: direct global gather (footprint exceeded cap) ----
        for (int o = tid; o < CH * BINS; o += 256) {
            int ch  = o / BINS;
            int bin = o - ch * BINS;
            int ph  = bin / ROI_OUT;
            int pw  = bin - ph * ROI_OUT;
            const float* plane = base0 + (size_t)ch * plane_sz;
            float acc = 0.0f;
            #pragma unroll
            for (int sy = 0; sy < 2; ++sy) {
                int4 py  = pY[2 * ph + sy];
                int  r0  = py.x * W;
                int  r1  = py.y * W;
                float ly = __int_as_float(py.z);
                float vy = __int_as_float(py.w);
                float hy = 1.0f - ly;
                #pragma unroll
                for (int sx = 0; sx < 2; ++sx) {
                    int4 px  = pX[2 * pw + sx];
                    float lx = __int_as_float(px.z);
                    float vx = __int_as_float(px.w);
                    float hx = 1.0f - lx;
                    float v00 = plane[r0 + px.x], v01 = plane[r0 + px.y];
                    float v10 = plane[r1 + px.x], v11 = plane[r1 + px.y];
                    acc += vy * vx * (hy * (hx * v00 + lx * v01)
                                    + ly * (hx * v10 + lx * v11));
                }
            }
            out[robase + o] = acc * 0.25f;
        }
    }
}

extern "C" void kernel_launch(void* const* d_in, const int* in_sizes, int n_in,
                              void* d_out, int out_size, void* d_ws, size_t ws_size,
                              hipStream_t stream)
{
    const float* f0    = (const float*)d_in[0];
    const float* f1    = (const float*)d_in[1];
    const float* f2    = (const float*)d_in[2];
    const float* f3    = (const float*)d_in[3];
    const float* boxes = (const float*)d_in[4];
    float* out = (float*)d_out;

    int rois = 2 * N_PER_B;                    // 512
    dim3 grid(rois * NCHUNK);                  // 16384 blocks
    hipLaunchKernelGGL(msroi_kernel, grid, dim3(256), 0, stream,
                       f0, f1, f2, f3, boxes, out);
}